// Round 1
// 907.954 us; speedup vs baseline: 1.0808x; 1.0808x over previous
//
#include <hip/hip_runtime.h>
#include <stdint.h>
#include <math.h>

// Problem constants
constexpr int Bb = 8, Tt = 512, Hh = 2048, Vv = 32000;
constexpr int M = Bb * Tt;     // 4096 tokens
constexpr int K = Hh;          // 2048
constexpr int N = Vv;          // 32000 vocab
constexpr int BM = 256, BN = 256, BK = 64;
constexpr int MBLK = M / BM;   // 16
constexpr int NBLK = N / BN;   // 125 column blocks
constexpr int KTILES = K / BK; // 32 (even)
constexpr int IGNORE = -100;

typedef __attribute__((ext_vector_type(8))) short bf16x8;
typedef __attribute__((ext_vector_type(4))) float f32x4;

__device__ inline void gld16(const void* g, void* l) {
  __builtin_amdgcn_global_load_lds(
      (const __attribute__((address_space(1))) uint32_t*)g,
      (__attribute__((address_space(3))) uint32_t*)l, 16, 0, 0);
}

// raw s_barrier with compiler memory fences on both sides (NOT __syncthreads:
// that drains vmcnt(0) and kills the counted-vmcnt pipeline).
__device__ __forceinline__ void barrier_f() {
  asm volatile("" ::: "memory");
  __builtin_amdgcn_s_barrier();
  asm volatile("" ::: "memory");
}

__device__ inline unsigned short f2bf(float f) {
  union { float f; unsigned u; } x; x.f = f;
  unsigned r = x.u + 0x7fffu + ((x.u >> 16) & 1u);  // RNE
  return (unsigned short)(r >> 16);
}

// ---------------- cast fp32 -> bf16, vectorized ----------------
__global__ void cast_bf16_kernel(const float* __restrict__ src,
                                 unsigned short* __restrict__ dst, int n4) {
  int i = blockIdx.x * blockDim.x + threadIdx.x;
  int stride = gridDim.x * blockDim.x;
  const float4* s4 = (const float4*)src;
  ushort4* d4 = (ushort4*)dst;
  for (; i < n4; i += stride) {
    float4 v = s4[i];
    ushort4 o;
    o.x = f2bf(v.x); o.y = f2bf(v.y); o.z = f2bf(v.z); o.w = f2bf(v.w);
    d4[i] = o;
  }
}

// ---------------- 256x256 8-phase GEMM + fused softmax-stats epilogue --------
//
// 8 waves (2M x 4N), each owns a 128x64 output tile = 8x4 MFMA fragments.
// LDS: As[2 buf][2 khalf][256 rows][32 k] bf16 (64 KB) + same for B (64 KB)
// + 8 KB reduction arrays = 136 KB -> 1 block/CU by design (template relies
// on per-phase ILP + counted vmcnt, not TLP).
//
// Per K-tile (BK=64): 4 phases (ksub0/m0-3, ksub0/m4-7, ksub1/m0-3, ksub1/m4-7);
// each phase: {4 (or 4+4) ds_read_b128} -> {stage one 16KB K-half via 2x
// global_load_lds dwordx4/thread} -> [vmcnt(4) at phases 4,8 only] -> s_barrier
// -> lgkmcnt(0) -> setprio(1) -> 16 MFMA -> setprio(0) -> s_barrier.
//
// Stage schedule (iter i computes tiles T0=2i (buf0), T1=2i+1 (buf1)); each
// half-tile is staged exactly ONE phase after its LDS region's last reader
// (write-after-read safe via the phase barriers):
//   p1: A1(T1)  p2: B1(T1)  p3: A0(T0+2)  p4: B0(T0+2)+vmcnt(4)
//   p5: A1(T0+2) p6: B1(T0+2) p7: A0(T1+2) p8: B0(T1+2)+vmcnt(4)
// In-order vmem completion => at each vmcnt(4) the 2 newest halves may remain
// outstanding and everything the next 4 phases read has landed. Steady-state
// per-wave in-flight: 4..12 loads, never drained to 0 in the main loop.
//
// LDS swizzle: within a K-half row (32 bf16 = 4x16B chunks), physical chunk =
// logical ^ ((row>>1)&3). Applied on the GLOBAL source address at staging
// (loop-invariant (lane&3)^((lane>>3)&3)) so global_load_lds keeps its linear
// wave-uniform dest; ds_read_b128 fragment reads then spread 2 lanes/bank.

template <int BUF, int KS, int MH, int VM, class STG>
__device__ __forceinline__ void phase(const unsigned short* __restrict__ AsB,
                                      const unsigned short* __restrict__ BsB,
                                      const int* offA, const int* offB,
                                      bf16x8 (&bfrag)[4], f32x4 (&acc)[8][4],
                                      STG&& stg) {
  const unsigned short* Ab = AsB + (BUF * 2 + KS) * 8192;
  if (MH == 0) {  // B fragments loaded once per K-subtile, reused by MH==1
    const unsigned short* Bp = BsB + (BUF * 2 + KS) * 8192;
#pragma unroll
    for (int nf = 0; nf < 4; ++nf) bfrag[nf] = *(const bf16x8*)(Bp + offB[nf]);
  }
  bf16x8 af[4];
#pragma unroll
  for (int mi = 0; mi < 4; ++mi) af[mi] = *(const bf16x8*)(Ab + offA[MH * 4 + mi]);
  stg();
  if (VM == 4) asm volatile("s_waitcnt vmcnt(4)" ::: "memory");
  if (VM == 0) asm volatile("s_waitcnt vmcnt(0)" ::: "memory");
  barrier_f();
  asm volatile("s_waitcnt lgkmcnt(0)" ::: "memory");
  __builtin_amdgcn_s_setprio(1);
#pragma unroll
  for (int mi = 0; mi < 4; ++mi)
#pragma unroll
    for (int nf = 0; nf < 4; ++nf)
      acc[MH * 4 + mi][nf] = __builtin_amdgcn_mfma_f32_16x16x32_bf16(
          af[mi], bfrag[nf], acc[MH * 4 + mi][nf], 0, 0, 0);
  __builtin_amdgcn_s_setprio(0);
  barrier_f();
}

__global__ __launch_bounds__(512, 2)
void gemm_stats(const unsigned short* __restrict__ X,
                const unsigned short* __restrict__ W,
                const float* __restrict__ bias,
                const int* __restrict__ tgt,
                float* __restrict__ m_part,
                float* __restrict__ s_part,
                float* __restrict__ tlogit) {
  extern __shared__ unsigned short smem[];
  unsigned short* AsB = smem;             // [2][2][256*32] = 32768 shorts (64KB)
  unsigned short* BsB = smem + 32768;     // 64KB
  float* red_m = (float*)(smem + 65536);  // [4][256] (4KB)
  float* red_s = red_m + 1024;            // [4][256] (4KB)

  const int tid = threadIdx.x;
  const int lane = tid & 63;
  const int wid = tid >> 6;        // 0..7
  const int waveM = wid >> 2;      // 0..1 (128 rows each)
  const int waveN = wid & 3;       // 0..3 (64 cols each)
  const int q = lane >> 4;         // 0..3
  const int c = lane & 15;

  // XCD-aware bijective swizzle: 2000 blocks, 2000 % 8 == 0, chunk = 250.
  // bm fastest within a chunk -> 16 same-bn blocks (sharing the 1MB W-tile)
  // land on the same XCD's L2.
  const int swz = (blockIdx.x & 7) * (MBLK * NBLK / 8) + (blockIdx.x >> 3);
  const int bm = swz & (MBLK - 1);
  const int bn = swz >> 4;  // /MBLK

  // ---- staging source addresses (pre-swizzled global -> linear LDS dest) ----
  const int srow = tid >> 2;                          // 0..127 (round j adds 128)
  const int sch = (lane & 3) ^ ((lane >> 3) & 3);     // swizzled 16B chunk 0..3
  const unsigned short* gA = X + (size_t)(bm * BM + srow) * K + sch * 8;
  const unsigned short* gB = W + (size_t)(bn * BN + srow) * K + sch * 8;
  unsigned short* const dA0 = AsB + wid * 512;        // wave-uniform dest base
  unsigned short* const dB0 = BsB + wid * 512;

  auto stA = [&](int b, int h, int t) {
    const unsigned short* s = gA + t * BK + h * 32;
    unsigned short* d = dA0 + (b * 2 + h) * 8192;
    gld16(s, d);                                  // rows 0..127 of the half
    gld16(s + (size_t)128 * K, d + 4096);         // rows 128..255
  };
  auto stB = [&](int b, int h, int t) {
    const unsigned short* s = gB + t * BK + h * 32;
    unsigned short* d = dB0 + (b * 2 + h) * 8192;
    gld16(s, d);
    gld16(s + (size_t)128 * K, d + 4096);
  };

  // ---- fragment read offsets (shorts, within one [256][32] K-half) ----
  const int chrd = (q ^ ((c >> 1) & 3)) * 8;  // swizzled chunk read offset
  int offA[8], offB[4];
#pragma unroll
  for (int mf = 0; mf < 8; ++mf) offA[mf] = (waveM * 128 + mf * 16 + c) * 32 + chrd;
#pragma unroll
  for (int nf = 0; nf < 4; ++nf) offB[nf] = (waveN * 64 + nf * 16 + c) * 32 + chrd;

  f32x4 acc[8][4];
#pragma unroll
  for (int i = 0; i < 8; ++i)
#pragma unroll
    for (int j = 0; j < 4; ++j) acc[i][j] = (f32x4){0.f, 0.f, 0.f, 0.f};
  bf16x8 bfrag[4];

  // ---- prologue: tile0 complete + tile1 k-half0; leave the 2 newest halves
  // in flight (they are consumed at p5, covered by the p4 vmcnt(4)). ----
  stA(0, 0, 0); stB(0, 0, 0);
  stA(0, 1, 0); stB(0, 1, 0);
  stA(1, 0, 1); stB(1, 0, 1);
  asm volatile("s_waitcnt vmcnt(4)" ::: "memory");
  barrier_f();

  for (int i = 0; i < KTILES / 2 - 1; ++i) {
    const int t0 = 2 * i;
    phase<0, 0, 0, -1>(AsB, BsB, offA, offB, bfrag, acc, [&] { stA(1, 1, t0 + 1); });
    phase<0, 0, 1, -1>(AsB, BsB, offA, offB, bfrag, acc, [&] { stB(1, 1, t0 + 1); });
    phase<0, 1, 0, -1>(AsB, BsB, offA, offB, bfrag, acc, [&] { stA(0, 0, t0 + 2); });
    phase<0, 1, 1,  4>(AsB, BsB, offA, offB, bfrag, acc, [&] { stB(0, 0, t0 + 2); });
    phase<1, 0, 0, -1>(AsB, BsB, offA, offB, bfrag, acc, [&] { stA(0, 1, t0 + 2); });
    phase<1, 0, 1, -1>(AsB, BsB, offA, offB, bfrag, acc, [&] { stB(0, 1, t0 + 2); });
    phase<1, 1, 0, -1>(AsB, BsB, offA, offB, bfrag, acc, [&] { stA(1, 0, t0 + 3); });
    phase<1, 1, 1,  4>(AsB, BsB, offA, offB, bfrag, acc, [&] { stB(1, 0, t0 + 3); });
  }
  {  // tail: tiles 30,31 — only tile31's k-half1 still needs staging
    auto nop = [&] {};
    phase<0, 0, 0, -1>(AsB, BsB, offA, offB, bfrag, acc, [&] { stA(1, 1, KTILES - 1); });
    phase<0, 0, 1, -1>(AsB, BsB, offA, offB, bfrag, acc, [&] { stB(1, 1, KTILES - 1); });
    phase<0, 1, 0, -1>(AsB, BsB, offA, offB, bfrag, acc, nop);
    phase<0, 1, 1,  0>(AsB, BsB, offA, offB, bfrag, acc, nop);
    phase<1, 0, 0, -1>(AsB, BsB, offA, offB, bfrag, acc, nop);
    phase<1, 0, 1, -1>(AsB, BsB, offA, offB, bfrag, acc, nop);
    phase<1, 1, 0, -1>(AsB, BsB, offA, offB, bfrag, acc, nop);
    phase<1, 1, 1, -1>(AsB, BsB, offA, offB, bfrag, acc, nop);
  }

  // ---- epilogue: per-row (max, sumexp) over this block's 256 columns ----
  // C/D layout (verified): col = lane&15, row = (lane>>4)*4 + reg.
  const int colBase = bn * BN + waveN * 64;
  float bvals[4];
#pragma unroll
  for (int nf = 0; nf < 4; ++nf) bvals[nf] = bias[colBase + nf * 16 + c];

#pragma unroll
  for (int mf = 0; mf < 8; ++mf) {
    const int rowBase = bm * BM + waveM * 128 + mf * 16 + q * 4;
#pragma unroll
    for (int reg = 0; reg < 4; ++reg) {
      const int grow = rowBase + reg;
      const int t = tgt[grow];
      float v[4];
      float mloc = -3.4e38f;
#pragma unroll
      for (int nf = 0; nf < 4; ++nf) {
        v[nf] = acc[mf][nf][reg] + bvals[nf];
        mloc = fmaxf(mloc, v[nf]);
        if (colBase + nf * 16 + c == t) tlogit[grow] = v[nf];  // one lane/block
      }
#pragma unroll
      for (int off = 1; off < 16; off <<= 1) mloc = fmaxf(mloc, __shfl_xor(mloc, off));
      float sloc = 0.f;
#pragma unroll
      for (int nf = 0; nf < 4; ++nf) sloc += __expf(v[nf] - mloc);
#pragma unroll
      for (int off = 1; off < 16; off <<= 1) sloc += __shfl_xor(sloc, off);
      if (c == 0) {
        const int lrow = waveM * 128 + mf * 16 + q * 4 + reg;
        red_m[waveN * 256 + lrow] = mloc;
        red_s[waveN * 256 + lrow] = sloc;
      }
    }
  }
  __syncthreads();
  if (tid < 256) {
    const float m0 = red_m[tid],       m1 = red_m[256 + tid];
    const float m2 = red_m[512 + tid], m3 = red_m[768 + tid];
    const float mx = fmaxf(fmaxf(m0, m1), fmaxf(m2, m3));
    const float ss = red_s[tid] * __expf(m0 - mx) + red_s[256 + tid] * __expf(m1 - mx) +
                     red_s[512 + tid] * __expf(m2 - mx) + red_s[768 + tid] * __expf(m3 - mx);
    const int grow = bm * BM + tid;
    m_part[(size_t)grow * NBLK + bn] = mx;
    s_part[(size_t)grow * NBLK + bn] = ss;
  }
}

// ---------------- combine per-row partials -> per-token logp ----------------
__global__ __launch_bounds__(256)
void combine_rows(const float* __restrict__ m_part, const float* __restrict__ s_part,
                  const float* __restrict__ tlogit, const int* __restrict__ tgt,
                  float* __restrict__ logp) {
  const int row = blockIdx.x * 4 + (threadIdx.x >> 6);
  const int lane = threadIdx.x & 63;
  const float* mrow = m_part + (size_t)row * NBLK;
  const float* srow = s_part + (size_t)row * NBLK;
  const bool v1 = (lane + 64) < NBLK;  // NBLK = 125
  const float m0 = mrow[lane];
  const float s0 = srow[lane];
  const float m1 = v1 ? mrow[lane + 64] : -3.4e38f;
  const float s1 = v1 ? srow[lane + 64] : 0.f;
  float mx = fmaxf(m0, m1);
#pragma unroll
  for (int off = 32; off >= 1; off >>= 1) mx = fmaxf(mx, __shfl_xor(mx, off));
  float s = s0 * __expf(m0 - mx) + s1 * __expf(m1 - mx);
#pragma unroll
  for (int off = 32; off >= 1; off >>= 1) s += __shfl_xor(s, off);
  if (lane == 0) {
    const int t = tgt[row];
    logp[row] = (t == IGNORE) ? 0.f : (tlogit[row] - mx - logf(s));
  }
}

// ---------------- per-sequence average + SimPO loss ----------------
__global__ void finalize(const float* __restrict__ logp, const int* __restrict__ tgt,
                         float* __restrict__ out) {
  __shared__ float avg[8];
  const int w = threadIdx.x >> 6;  // 8 waves, one per sequence
  const int lane = threadIdx.x & 63;
  float s = 0.f, cnt = 0.f;
  for (int i = lane; i < Tt; i += 64) {
    const int idx = w * Tt + i;
    s += logp[idx];
    cnt += (tgt[idx] != IGNORE) ? 1.f : 0.f;
  }
#pragma unroll
  for (int off = 32; off >= 1; off >>= 1) {
    s += __shfl_xor(s, off);
    cnt += __shfl_xor(cnt, off);
  }
  if (lane == 0) avg[w] = s / fmaxf(cnt, 1.f);
  __syncthreads();
  if (threadIdx.x == 0) {
    float loss = 0.f;
#pragma unroll
    for (int p = 0; p < 4; ++p) {
      const float d = 0.1f * (avg[p] - avg[p + 4]) - 0.5f;
      const float nl = (d > 0.f) ? log1pf(expf(-d)) : (-d + log1pf(expf(d)));
      loss += nl;
    }
    out[0] = loss * 0.25f;  // / n_pairs
  }
}

extern "C" void kernel_launch(void* const* d_in, const int* in_sizes, int n_in,
                              void* d_out, int out_size, void* d_ws, size_t ws_size,
                              hipStream_t stream) {
  const float* Wf   = (const float*)d_in[0];  // lin_weight (V,H)
  const float* Xf   = (const float*)d_in[1];  // _input (B,T,H)
  const int*   tgt  = (const int*)d_in[2];    // target (B,T)
  const float* bias = (const float*)d_in[3];  // bias (V,)
  float* out = (float*)d_out;

  char* ws = (char*)d_ws;
  size_t off = 0;
  auto alloc = [&](size_t bytes) {
    void* p = ws + off;
    off += (bytes + 255) & ~(size_t)255;
    return p;
  };
  unsigned short* Xbf = (unsigned short*)alloc((size_t)M * K * 2);
  unsigned short* Wbf = (unsigned short*)alloc((size_t)N * K * 2);
  float* m_part = (float*)alloc((size_t)M * NBLK * 4);
  float* s_part = (float*)alloc((size_t)M * NBLK * 4);
  float* tlog   = (float*)alloc((size_t)M * 4);
  float* logp   = (float*)alloc((size_t)M * 4);

  cast_bf16_kernel<<<2048, 256, 0, stream>>>(Xf, Xbf, M * K / 4);
  cast_bf16_kernel<<<8192, 256, 0, stream>>>(Wf, Wbf, N * K / 4);

  constexpr size_t SMEM = 2u * 2u * 256u * 32u * 2u * 2u  // A + B (128 KB)
                        + 2u * 4u * 256u * 4u;            // red_m + red_s (8 KB)
  gemm_stats<<<dim3(MBLK * NBLK), dim3(512), SMEM, stream>>>(
      Xbf, Wbf, bias, tgt, m_part, s_part, tlog);

  combine_rows<<<M / 4, 256, 0, stream>>>(m_part, s_part, tlog, tgt, logp);
  finalize<<<1, 512, 0, stream>>>(logp, tgt, out);
}